// Round 24
// baseline (253.049 us; speedup 1.0000x reference)
//
#include <hip/hip_runtime.h>
#include <hip/hip_cooperative_groups.h>

namespace cg = cooperative_groups;

typedef unsigned int u32;
typedef unsigned long long u64;

#define BB 4
#define NN 261888
#define KSEL 6000
#define CAP 8192
#define PC 1000
#define NMS_THR 0.7f
#define NW 94
#define NWP 96
#define NR (NW*64)
#define COLSPLIT 6

#define HB 31
#define CHUNK_H (NN/HB)          /* 8448 = 33*256 */
#define HITER (CHUNK_H/256)      /* 33 */

#define CS 4
#define CPS (CAP/CS)

// ---------------- ws layout (u32 units) ----------------
#define HIST1_OFF 0
#define HIST2_OFF (BB*2048)
#define SEL_OFF   (BB*2048*2)
#define CNT_OFF   (BB*2048*2 + BB*4)
#define RANK_OFF  (BB*2048*2 + BB*4 + BB*32)
#define ZERO_WORDS (BB*2048*2 + BB*4 + BB*32 + BB*CAP)

__global__ void k_zero(u32* ws) {
    int i = blockIdx.x * 256 + threadIdx.x;
    if (i < ZERO_WORDS) ws[i] = 0u;
}

// ---------- fused cooperative select: hist1+sel1+hist2+sel2+compact ----------
// grid (HB, BB) x 256. Keys loaded ONCE into registers (33/thread); one pass
// over probs instead of three; grid.sync() between phases.
__global__ void k_select(const float2* __restrict__ probs2,
                         u32* __restrict__ hist1, u32* __restrict__ hist2,
                         u32* __restrict__ sel, u32* __restrict__ candCount,
                         u64* __restrict__ cand) {
    cg::grid_group grid = cg::this_grid();
    __shared__ u32 lh[2048];
    __shared__ u32 gsum[256];
    __shared__ u32 wsum[4];
    __shared__ u32 blkBase;
    int b = blockIdx.y;
    int tid = threadIdx.x;
    int wave = tid >> 6, lane = tid & 63;
    size_t base = (size_t)b * NN + (size_t)blockIdx.x * CHUNK_H;

    u32 keys[HITER];

    // phase 1: load keys + LDS hist1 + flush
    for (int j = tid; j < 2048; j += 256) lh[j] = 0u;
    __syncthreads();
    #pragma unroll
    for (int it = 0; it < HITER; ++it) {
        float2 p = probs2[base + it * 256 + tid];
        keys[it] = __float_as_uint(p.y);
        atomicAdd(&lh[keys[it] >> 21], 1u);
    }
    __syncthreads();
    for (int j = tid; j < 2048; j += 256) {
        u32 c = lh[j];
        if (c) atomicAdd(&hist1[b * 2048 + j], c);
    }
    grid.sync();

    // phase 2: sel1 (block x==0 of each batch)
    if (blockIdx.x == 0) {
        u32 s = 0;
        #pragma unroll
        for (int j = 0; j < 8; ++j) {
            u32 v = hist1[b * 2048 + 2047 - (tid * 8 + j)];
            lh[tid * 8 + j] = v;
            s += v;
        }
        gsum[tid] = s;
        __syncthreads();
        if (tid == 0) {
            u32 cum = 0;
            for (int g = 0; g < 256; ++g) {
                if (cum + gsum[g] >= (u32)KSEL) {
                    for (int j = 0; j < 8; ++j) {
                        u32 c = lh[g * 8 + j];
                        if (cum + c >= (u32)KSEL) {
                            sel[b * 4 + 0] = (u32)(2047 - (g * 8 + j));
                            sel[b * 4 + 1] = cum;
                            break;
                        }
                        cum += c;
                    }
                    break;
                }
                cum += gsum[g];
            }
        }
    }
    grid.sync();

    // phase 3: hist2 from registers
    u32 b1 = sel[b * 4 + 0];
    for (int j = tid; j < 2048; j += 256) lh[j] = 0u;
    __syncthreads();
    #pragma unroll
    for (int it = 0; it < HITER; ++it) {
        u32 key = keys[it];
        if ((key >> 21) == b1) atomicAdd(&lh[(key >> 10) & 2047u], 1u);
    }
    __syncthreads();
    for (int j = tid; j < 2048; j += 256) {
        u32 c = lh[j];
        if (c) atomicAdd(&hist2[b * 2048 + j], c);
    }
    grid.sync();

    // phase 4: sel2
    if (blockIdx.x == 0) {
        u32 s = 0;
        #pragma unroll
        for (int j = 0; j < 8; ++j) {
            u32 v = hist2[b * 2048 + 2047 - (tid * 8 + j)];
            lh[tid * 8 + j] = v;
            s += v;
        }
        gsum[tid] = s;
        __syncthreads();
        if (tid == 0) {
            u32 cum = sel[b * 4 + 1];
            for (int g = 0; g < 256; ++g) {
                if (cum + gsum[g] >= (u32)KSEL) {
                    for (int j = 0; j < 8; ++j) {
                        cum += lh[g * 8 + j];
                        if (cum >= (u32)KSEL) {
                            sel[b * 4 + 2] = (b1 << 11) | (u32)(2047 - (g * 8 + j));
                            break;
                        }
                    }
                    break;
                }
                cum += gsum[g];
            }
        }
    }
    grid.sync();

    // phase 5: compact from registers (ballot-scan, one atomic per block)
    u32 thr = sel[b * 4 + 2];
    u32 cnt = 0;
    #pragma unroll
    for (int it = 0; it < HITER; ++it)
        cnt += ((keys[it] >> 10) >= thr) ? 1u : 0u;
    #pragma unroll
    for (int off = 32; off; off >>= 1) cnt += __shfl_down(cnt, off);
    if (lane == 0) wsum[wave] = cnt;
    __syncthreads();
    if (tid == 0) {
        u32 w0 = wsum[0], w1 = wsum[1], w2 = wsum[2], w3 = wsum[3];
        u32 tot = w0 + w1 + w2 + w3;
        wsum[0] = 0; wsum[1] = w0; wsum[2] = w0 + w1; wsum[3] = w0 + w1 + w2;
        blkBase = tot ? atomicAdd(&candCount[b * 32], tot) : 0u;
    }
    __syncthreads();
    u32 run = blkBase + wsum[wave];
    u64* cb = cand + (size_t)b * CAP;
    u32 cbase = (u32)blockIdx.x * CHUNK_H;
    #pragma unroll
    for (int it = 0; it < HITER; ++it) {
        u32 key = keys[it];
        bool pred = (key >> 10) >= thr;
        u64 m = __ballot(pred);
        if (pred) {
            u32 pos = run + (u32)__popcll(m & ((1ull << lane) - 1ull));
            u32 gi = cbase + it * 256 + tid;
            if (pos < CAP) cb[pos] = ((u64)key << 32) | (u32)(~gi);
        }
        run += (u32)__popcll(m);
    }
}

// ---------- rank: column-sliced partial rank, atomic accumulate ----------
__global__ __launch_bounds__(512) void k_rank(const u64* __restrict__ cand,
                                              const u32* __restrict__ candCount,
                                              u32* __restrict__ rankArr) {
    __shared__ u64 keys[CPS];
    int b = blockIdx.z;
    int c0 = blockIdx.y * CPS;
    int tid = threadIdx.x;
    int cnt = (int)candCount[b * 32];
    if (cnt > CAP) cnt = CAP;
    const u64* cb = cand + (size_t)b * CAP;
    for (int j = tid; j < CPS; j += 512)
        keys[j] = (c0 + j < cnt) ? cb[c0 + j] : 0ull;
    __syncthreads();
    int r = blockIdx.x * 512 + tid;
    if (r >= cnt) return;
    u64 my = cb[r];
    u32 rank = 0;
    for (int j = 0; j < CPS; j += 16) {
        #pragma unroll
        for (int u = 0; u < 16; ++u)
            rank += (keys[j + u] > my) ? 1u : 0u;
    }
    if (rank) atomicAdd(&rankArr[b * CAP + r], rank);
}

// ---------- fused scatter+decode ----------
__global__ void k_scatterdecode(const u64* __restrict__ cand, const u32* __restrict__ candCount,
                                const u32* __restrict__ rankArr,
                                const float4* __restrict__ anchors,
                                const float4* __restrict__ deltas,
                                float4* __restrict__ boxes) {
    int b = blockIdx.y;
    int p = blockIdx.x * 256 + threadIdx.x;
    int cnt = (int)candCount[b * 32];
    if (cnt > CAP) cnt = CAP;
    if (p >= cnt) return;
    u32 rank = rankArr[b * CAP + p];
    if (rank >= KSEL) return;
    u64 sk = cand[(size_t)b * CAP + p];
    u32 idx = ~(u32)(sk & 0xFFFFFFFFull);
    if (idx >= NN) idx = NN - 1;
    float4 a = anchors[(size_t)b * NN + idx];
    float4 d = deltas[(size_t)b * NN + idx];
    float dy = __fmul_rn(d.x, 0.1f);
    float dx = __fmul_rn(d.y, 0.1f);
    float dh = __fmul_rn(d.z, 0.2f);
    float dw = __fmul_rn(d.w, 0.2f);
    float h  = __fsub_rn(a.z, a.x);
    float w  = __fsub_rn(a.w, a.y);
    float cy = __fadd_rn(__fadd_rn(a.x, __fmul_rn(0.5f, h)), __fmul_rn(dy, h));
    float cx = __fadd_rn(__fadd_rn(a.y, __fmul_rn(0.5f, w)), __fmul_rn(dx, w));
    float h2 = __fmul_rn(h, expf(dh));
    float w2 = __fmul_rn(w, expf(dw));
    float y1 = __fsub_rn(cy, __fmul_rn(0.5f, h2));
    float x1 = __fsub_rn(cx, __fmul_rn(0.5f, w2));
    float y2 = __fadd_rn(y1, h2);
    float x2 = __fadd_rn(x1, w2);
    y1 = fminf(fmaxf(y1, 0.0f), 1.0f);
    x1 = fminf(fmaxf(x1, 0.0f), 1.0f);
    y2 = fminf(fmaxf(y2, 0.0f), 1.0f);
    x2 = fminf(fmaxf(x2, 0.0f), 1.0f);
    float4 out;
    out.x = y1; out.y = x1; out.z = y2; out.w = x2;
    boxes[(size_t)b * KSEL + rank] = out;
}

// ---------- phase 1: upper-triangle bitmask, row-major, stride NWP ----------
__global__ __launch_bounds__(256) void k_iou(const float4* __restrict__ boxes,
                                             u64* __restrict__ mask) {
    __shared__ float4 colBox[4][64];
    __shared__ float  colArea[4][64];
    int b = blockIdx.z;
    int rblk = blockIdx.x;
    int r0 = rblk * 64;
    int tid = threadIdx.x;
    int wave = tid >> 6, lane = tid & 63;
    const float4* B4 = boxes + (size_t)b * KSEL;

    int r = r0 + lane;
    float4 rb;
    if (r < KSEL) rb = B4[r];
    else { rb.x = 2.0f; rb.y = 2.0f; rb.z = 3.0f; rb.w = 3.0f; }
    float ra = __fmul_rn(__fsub_rn(rb.z, rb.x), __fsub_rn(rb.w, rb.y));

    const double M0 = 0.5 * ((double)__uint_as_float(0x3F333333u)
                           + (double)__uint_as_float(0x3F333334u));
    u64* Mb = mask + (size_t)b * NR * NWP;

    for (int jw = rblk + blockIdx.y * 4 + wave; jw < NW; jw += 4 * COLSPLIT) {
        int j = jw * 64 + lane;
        float4 cbx;
        if (j < KSEL) cbx = B4[j];
        else { cbx.x = 2.0f; cbx.y = 2.0f; cbx.z = 3.0f; cbx.w = 3.0f; }
        colBox[wave][lane] = cbx;
        colArea[wave][lane] = __fmul_rn(__fsub_rn(cbx.z, cbx.x), __fsub_rn(cbx.w, cbx.y));
        asm volatile("" ::: "memory");

        u64 word = 0ull;
        #pragma unroll
        for (int c = 0; c < 64; ++c) {
            float4 cb = colBox[wave][c];
            float ca = colArea[wave][c];
            float ih = fmaxf(__fsub_rn(fminf(rb.z, cb.z), fmaxf(rb.x, cb.x)), 0.0f);
            float iw = fmaxf(__fsub_rn(fminf(rb.w, cb.w), fmaxf(rb.y, cb.y)), 0.0f);
            float inter = __fmul_rn(ih, iw);
            float denom = __fadd_rn(__fsub_rn(__fadd_rn(ra, ca), inter), 1e-8f);
            bool pred = ((double)inter >= M0 * (double)denom);
            word |= ((u64)pred) << c;
        }
        Mb[(size_t)(r0 + lane) * NWP + jw] = word;
        asm volatile("" ::: "memory");
    }
}

// ---------- phase 2: 16-wave reduce (structural floor ~70us, 5 variants) ----------
__device__ __forceinline__ u64 readlane64(u64 v, int lane) {
    u32 lo = (u32)__builtin_amdgcn_readlane((int)(u32)v, lane);
    u32 hi = (u32)__builtin_amdgcn_readlane((int)(u32)(v >> 32), lane);
    return ((u64)hi << 32) | (u64)lo;
}
__device__ __forceinline__ u64 rfl64(u64 v) {
    u32 lo = (u32)__builtin_amdgcn_readfirstlane((int)(u32)v);
    u32 hi = (u32)__builtin_amdgcn_readfirstlane((int)(u32)(v >> 32));
    return ((u64)hi << 32) | (u64)lo;
}
__device__ __forceinline__ void barrier_lds_only() {
    asm volatile("s_waitcnt lgkmcnt(0)" ::: "memory");
    __builtin_amdgcn_s_barrier();
    asm volatile("" ::: "memory");
}

__global__ __launch_bounds__(1024) void k_reduce(const u64* __restrict__ mask,
                                                 const float4* __restrict__ boxes,
                                                 float* __restrict__ outp) {
    __shared__ u64 pub[16];
    __shared__ u64 kbLDS;
    __shared__ u32 kLDS;
    __shared__ u32 keptIdx[PC];
    int b = blockIdx.x;
    int tid = threadIdx.x;
    int wv = tid >> 6, lane = tid & 63;
    const u64* M = mask + (size_t)b * NR * NWP;
    const float4* B4 = boxes + (size_t)b * KSEL;
    int lp = lane < 46 ? lane : 46;
    u64 rwA = 0ull, rwB = 0ull;
    int k = 0, kprev = 0;
    bool done = false;

    if (tid < 16) pub[tid] = 0ull;

    ulonglong2 bufA[4], bufB[4], bufC[4];
    u64 dgA, dgB, dgC;

#define LOADG(BUF, DG, gg) do {                                               \
    int gl_ = (gg); if (gl_ > NW - 1) gl_ = NW - 1;                           \
    _Pragma("unroll")                                                         \
    for (int r_ = 0; r_ < 4; ++r_)                                            \
        BUF[r_] = *(const ulonglong2*)(M + (size_t)(gl_ * 64 + wv * 4 + r_) * NWP + 2 * lp); \
    DG = M[(size_t)(gl_ * 64 + lane) * NWP + gl_];                            \
} while (0)

#define BODY(gg, CUR, DGC, NXT, DGN) do {                                     \
    const int gb_ = (gg);                                                     \
    LOADG(NXT, DGN, gb_ + 2);                                                 \
    if (wv == 0) {                                                            \
        u64 rem = pub[0] | pub[1] | pub[2] | pub[3]                           \
                | pub[4] | pub[5] | pub[6] | pub[7]                           \
                | pub[8] | pub[9] | pub[10] | pub[11]                         \
                | pub[12] | pub[13] | pub[14] | pub[15];                      \
        rem = rfl64(rem);                                                     \
        int remaining = KSEL - gb_ * 64;                                      \
        u64 valid = (remaining >= 64) ? ~0ull : ((1ull << remaining) - 1ull); \
        u64 todo = ~rem & valid;                                              \
        u64 kb0 = 0ull;                                                       \
        int k0 = k;                                                           \
        while (todo && k0 < PC) {                                             \
            u64 t_ = todo;                                                    \
            int i0 = (int)__builtin_ctzll(t_); t_ &= t_ - 1;                  \
            bool v1 = t_ != 0ull;                                             \
            int i1 = v1 ? (int)__builtin_ctzll(t_) : i0; t_ &= t_ - 1;        \
            bool v2 = t_ != 0ull;                                             \
            int i2 = v2 ? (int)__builtin_ctzll(t_) : i0; t_ &= t_ - 1;        \
            bool v3 = t_ != 0ull;                                             \
            int i3 = v3 ? (int)__builtin_ctzll(t_) : i0;                      \
            u64 m0 = __ballot(((DGC >> i0) & 1ull) != 0ull);                  \
            u64 m1 = __ballot(((DGC >> i1) & 1ull) != 0ull);                  \
            u64 m2 = __ballot(((DGC >> i2) & 1ull) != 0ull);                  \
            u64 m3 = __ballot(((DGC >> i3) & 1ull) != 0ull);                  \
            u64 kept_ = 1ull << i0; ++k0;                                     \
            u64 sup_ = m0;                                                    \
            if (v1 && k0 < PC && !((sup_ >> i1) & 1ull)) {                    \
                kept_ |= 1ull << i1; ++k0; sup_ |= m1;                        \
            }                                                                 \
            if (v2 && k0 < PC && !((sup_ >> i2) & 1ull)) {                    \
                kept_ |= 1ull << i2; ++k0; sup_ |= m2;                        \
            }                                                                 \
            if (v3 && k0 < PC && !((sup_ >> i3) & 1ull)) {                    \
                kept_ |= 1ull << i3; ++k0; sup_ |= m3;                        \
            }                                                                 \
            kb0 |= kept_;                                                     \
            todo &= ~(sup_ | kept_);                                          \
            if (k0 >= PC) break;                                              \
        }                                                                     \
        if ((kb0 >> lane) & 1ull) {                                           \
            int rank = kprev + (int)__popcll(kb0 & ((1ull << lane) - 1ull));  \
            keptIdx[rank] = (u32)(gb_ * 64 + lane);                           \
        }                                                                     \
        kprev = k0;                                                           \
        if (lane == 0) { kbLDS = kb0; kLDS = (u32)k0; }                       \
    }                                                                         \
    barrier_lds_only();                                                       \
    u64 kb_ = kbLDS;                                                          \
    k = (int)kLDS;                                                            \
    _Pragma("unroll")                                                         \
    for (int r_ = 0; r_ < 4; ++r_)                                            \
        if ((kb_ >> (wv * 4 + r_)) & 1ull) { rwA |= CUR[r_].x; rwB |= CUR[r_].y; } \
    if (k >= PC || gb_ == NW - 1) { done = true; }                            \
    else {                                                                    \
        int nw_ = gb_ + 1;                                                    \
        u64 wpub = (nw_ & 1) ? readlane64(rwB, nw_ >> 1)                      \
                             : readlane64(rwA, nw_ >> 1);                     \
        if (lane == 0) pub[wv] = wpub;                                        \
        barrier_lds_only();                                                   \
    }                                                                         \
} while (0)

    LOADG(bufA, dgA, 0);
    LOADG(bufB, dgB, 1);
    __syncthreads();

    for (int g = 0; g < NW && !done; g += 3) {
        BODY(g, bufA, dgA, bufC, dgC);
        if (done || g + 1 >= NW) break;
        BODY(g + 1, bufB, dgB, bufA, dgA);
        if (done || g + 2 >= NW) break;
        BODY(g + 2, bufC, dgC, bufB, dgB);
    }
    __syncthreads();

    float4* O = (float4*)outp + (size_t)b * PC;
    for (int t = tid; t < PC; t += 1024) {
        float4 v; v.x = 0.0f; v.y = 0.0f; v.z = 0.0f; v.w = 0.0f;
        if (t < k) v = B4[keptIdx[t]];
        O[t] = v;
    }
#undef LOADG
#undef BODY
}

extern "C" void kernel_launch(void* const* d_in, const int* in_sizes, int n_in,
                              void* d_out, int out_size, void* d_ws, size_t ws_size,
                              hipStream_t stream) {
    const float* probs   = (const float*)d_in[0];
    const float* deltas  = (const float*)d_in[1];
    const float* anchors = (const float*)d_in[2];
    float* outp = (float*)d_out;

    u32* ws32 = (u32*)d_ws;
    u32* hist1 = ws32 + HIST1_OFF;
    u32* hist2 = ws32 + HIST2_OFF;
    u32* sel   = ws32 + SEL_OFF;
    u32* candCount = ws32 + CNT_OFF;
    u32* rankArr   = ws32 + RANK_OFF;
    u64* cand   = (u64*)(ws32 + ZERO_WORDS);
    float* boxesF = (float*)(cand + (size_t)BB * CAP);
    float4* boxes = (float4*)boxesF;
    u64* mask = (u64*)(boxesF + (size_t)BB * KSEL * 4);

    hipLaunchKernelGGL(k_zero, dim3((ZERO_WORDS + 255) / 256), dim3(256), 0, stream, ws32);

    {
        const float2* probs2 = (const float2*)probs;
        void* args[] = { (void*)&probs2, (void*)&hist1, (void*)&hist2,
                         (void*)&sel, (void*)&candCount, (void*)&cand };
        hipLaunchCooperativeKernel((const void*)k_select, dim3(HB, BB), dim3(256),
                                   args, 0, stream);
    }

    hipLaunchKernelGGL(k_rank, dim3(CAP / 512, CS, BB), dim3(512), 0, stream, cand, candCount, rankArr);
    hipLaunchKernelGGL(k_scatterdecode, dim3(CAP / 256, BB), dim3(256), 0, stream,
                       cand, candCount, rankArr,
                       (const float4*)anchors, (const float4*)deltas, boxes);
    hipLaunchKernelGGL(k_iou, dim3(NW, COLSPLIT, BB), dim3(256), 0, stream, boxes, mask);
    hipLaunchKernelGGL(k_reduce, dim3(BB), dim3(1024), 0, stream, mask, boxes, outp);
}

// Round 25
// 213.536 us; speedup vs baseline: 1.1850x; 1.1850x over previous
//
#include <hip/hip_runtime.h>

typedef unsigned int u32;
typedef unsigned long long u64;

#define BB 4
#define NN 261888
#define KSEL 6000
#define CAP 8192
#define PC 1000
#define NMS_THR 0.7f
#define NW 94          /* words used */
#define NWP 96         /* padded row stride in words (768B rows, 16B aligned) */
#define NR (NW*64)     /* padded mask rows = 6016 */
#define COLSPLIT 6

#define HB 31
#define CHUNK_H (NN/HB)
#define HITER (CHUNK_H/256)
#define CB 93
#define CHUNK_C (NN/CB)
#define CITER (CHUNK_C/256)

#define CS 4             /* k_rank column slices */
#define CPS (CAP/CS)     /* 2048 columns per slice */

// ---------------- ws layout (u32 units) ----------------
#define HIST1_OFF 0
#define HIST2_OFF (BB*2048)
#define SEL_OFF   (BB*2048*2)
#define CNT_OFF   (BB*2048*2 + BB*4)
#define RANK_OFF  (BB*2048*2 + BB*4 + BB*32)
#define ZERO_WORDS (BB*2048*2 + BB*4 + BB*32 + BB*CAP)

__global__ void k_zero(u32* ws) {
    int i = blockIdx.x * 256 + threadIdx.x;
    if (i < ZERO_WORDS) ws[i] = 0u;
}

__global__ void k_hist1(const float2* __restrict__ probs2, u32* __restrict__ hist1) {
    __shared__ u32 lh[2048];
    int b = blockIdx.y;
    size_t base = (size_t)b * NN + (size_t)blockIdx.x * CHUNK_H;
    for (int j = threadIdx.x; j < 2048; j += 256) lh[j] = 0u;
    __syncthreads();
    #pragma unroll 4
    for (int it = 0; it < HITER; ++it) {
        float2 p = probs2[base + it * 256 + threadIdx.x];
        atomicAdd(&lh[__float_as_uint(p.y) >> 21], 1u);
    }
    __syncthreads();
    for (int j = threadIdx.x; j < 2048; j += 256) {
        u32 c = lh[j];
        if (c) atomicAdd(&hist1[b * 2048 + j], c);
    }
}

__global__ void k_sel1(const u32* __restrict__ hist1, u32* __restrict__ sel) {
    __shared__ u32 gsum[256];
    __shared__ u32 lh[2048];
    int b = blockIdx.x;
    int t = threadIdx.x;
    u32 s = 0;
    #pragma unroll
    for (int j = 0; j < 8; ++j) {
        u32 v = hist1[b * 2048 + 2047 - (t * 8 + j)];
        lh[t * 8 + j] = v;
        s += v;
    }
    gsum[t] = s;
    __syncthreads();
    if (t == 0) {
        u32 cum = 0;
        for (int g = 0; g < 256; ++g) {
            if (cum + gsum[g] >= (u32)KSEL) {
                for (int j = 0; j < 8; ++j) {
                    u32 c = lh[g * 8 + j];
                    if (cum + c >= (u32)KSEL) {
                        sel[b * 4 + 0] = (u32)(2047 - (g * 8 + j));
                        sel[b * 4 + 1] = cum;
                        break;
                    }
                    cum += c;
                }
                break;
            }
            cum += gsum[g];
        }
    }
}

__global__ void k_hist2(const float2* __restrict__ probs2, const u32* __restrict__ sel,
                        u32* __restrict__ hist2) {
    int b = blockIdx.y;
    u32 b1 = sel[b * 4 + 0];
    size_t base = (size_t)b * NN + (size_t)blockIdx.x * CHUNK_H;
    #pragma unroll 4
    for (int it = 0; it < HITER; ++it) {
        float2 p = probs2[base + it * 256 + threadIdx.x];
        u32 key = __float_as_uint(p.y);
        if ((key >> 21) == b1) atomicAdd(&hist2[b * 2048 + ((key >> 10) & 2047u)], 1u);
    }
}

__global__ void k_sel2(const u32* __restrict__ hist2, u32* __restrict__ sel) {
    __shared__ u32 gsum[256];
    __shared__ u32 lh[2048];
    int b = blockIdx.x;
    int t = threadIdx.x;
    u32 s = 0;
    #pragma unroll
    for (int j = 0; j < 8; ++j) {
        u32 v = hist2[b * 2048 + 2047 - (t * 8 + j)];
        lh[t * 8 + j] = v;
        s += v;
    }
    gsum[t] = s;
    __syncthreads();
    if (t == 0) {
        u32 cum = sel[b * 4 + 1];
        u32 b1 = sel[b * 4 + 0];
        for (int g = 0; g < 256; ++g) {
            if (cum + gsum[g] >= (u32)KSEL) {
                for (int j = 0; j < 8; ++j) {
                    cum += lh[g * 8 + j];
                    if (cum >= (u32)KSEL) {
                        sel[b * 4 + 2] = (b1 << 11) | (u32)(2047 - (g * 8 + j));
                        break;
                    }
                }
                break;
            }
            cum += gsum[g];
        }
    }
}

__global__ void k_compact(const float2* __restrict__ probs2, const u32* __restrict__ sel,
                          u32* __restrict__ candCount, u64* __restrict__ cand) {
    __shared__ u32 wsum[4];
    __shared__ u32 blkBase;
    int b = blockIdx.y;
    int tid = threadIdx.x;
    int wave = tid >> 6, lane = tid & 63;
    u32 base = (u32)blockIdx.x * CHUNK_C;
    u32 thr = sel[b * 4 + 2];

    u32 keys[CITER];
    u32 cnt = 0;
    #pragma unroll
    for (int it = 0; it < CITER; ++it) {
        float2 p = probs2[(size_t)b * NN + base + it * 256 + tid];
        u32 key = __float_as_uint(p.y);
        keys[it] = key;
        cnt += ((key >> 10) >= thr) ? 1u : 0u;
    }
    #pragma unroll
    for (int off = 32; off; off >>= 1) cnt += __shfl_down(cnt, off);
    if (lane == 0) wsum[wave] = cnt;
    __syncthreads();
    if (tid == 0) {
        u32 w0 = wsum[0], w1 = wsum[1], w2 = wsum[2], w3 = wsum[3];
        u32 tot = w0 + w1 + w2 + w3;
        wsum[0] = 0; wsum[1] = w0; wsum[2] = w0 + w1; wsum[3] = w0 + w1 + w2;
        blkBase = tot ? atomicAdd(&candCount[b * 32], tot) : 0u;
    }
    __syncthreads();
    u32 run = blkBase + wsum[wave];
    u64* cb = cand + (size_t)b * CAP;
    #pragma unroll
    for (int it = 0; it < CITER; ++it) {
        u32 key = keys[it];
        bool pred = (key >> 10) >= thr;
        u64 m = __ballot(pred);
        if (pred) {
            u32 pos = run + (u32)__popcll(m & ((1ull << lane) - 1ull));
            u32 gi = base + it * 256 + tid;
            if (pos < CAP) cb[pos] = ((u64)key << 32) | (u32)(~gi);
        }
        run += (u32)__popcll(m);
    }
}

// ---------- rank: column-sliced partial rank, atomic accumulate ----------
__global__ __launch_bounds__(512) void k_rank(const u64* __restrict__ cand,
                                              const u32* __restrict__ candCount,
                                              u32* __restrict__ rankArr) {
    __shared__ u64 keys[CPS];   // 16 KB
    int b = blockIdx.z;
    int c0 = blockIdx.y * CPS;
    int tid = threadIdx.x;
    int cnt = (int)candCount[b * 32];
    if (cnt > CAP) cnt = CAP;
    const u64* cb = cand + (size_t)b * CAP;
    for (int j = tid; j < CPS; j += 512)
        keys[j] = (c0 + j < cnt) ? cb[c0 + j] : 0ull;
    __syncthreads();
    int r = blockIdx.x * 512 + tid;
    if (r >= cnt) return;
    u64 my = cb[r];
    u32 rank = 0;
    for (int j = 0; j < CPS; j += 16) {
        #pragma unroll
        for (int u = 0; u < 16; ++u)
            rank += (keys[j + u] > my) ? 1u : 0u;
    }
    if (rank) atomicAdd(&rankArr[b * CAP + r], rank);
}

// ---------- fused scatter+decode: boxes[rank] = decode(key) ----------
__global__ void k_scatterdecode(const u64* __restrict__ cand, const u32* __restrict__ candCount,
                                const u32* __restrict__ rankArr,
                                const float4* __restrict__ anchors,
                                const float4* __restrict__ deltas,
                                float4* __restrict__ boxes) {
    int b = blockIdx.y;
    int p = blockIdx.x * 256 + threadIdx.x;
    int cnt = (int)candCount[b * 32];
    if (cnt > CAP) cnt = CAP;
    if (p >= cnt) return;
    u32 rank = rankArr[b * CAP + p];
    if (rank >= KSEL) return;
    u64 sk = cand[(size_t)b * CAP + p];
    u32 idx = ~(u32)(sk & 0xFFFFFFFFull);
    if (idx >= NN) idx = NN - 1;   // poison-safety
    float4 a = anchors[(size_t)b * NN + idx];
    float4 d = deltas[(size_t)b * NN + idx];
    float dy = __fmul_rn(d.x, 0.1f);
    float dx = __fmul_rn(d.y, 0.1f);
    float dh = __fmul_rn(d.z, 0.2f);
    float dw = __fmul_rn(d.w, 0.2f);
    float h  = __fsub_rn(a.z, a.x);
    float w  = __fsub_rn(a.w, a.y);
    float cy = __fadd_rn(__fadd_rn(a.x, __fmul_rn(0.5f, h)), __fmul_rn(dy, h));
    float cx = __fadd_rn(__fadd_rn(a.y, __fmul_rn(0.5f, w)), __fmul_rn(dx, w));
    float h2 = __fmul_rn(h, expf(dh));
    float w2 = __fmul_rn(w, expf(dw));
    float y1 = __fsub_rn(cy, __fmul_rn(0.5f, h2));
    float x1 = __fsub_rn(cx, __fmul_rn(0.5f, w2));
    float y2 = __fadd_rn(y1, h2);
    float x2 = __fadd_rn(x1, w2);
    y1 = fminf(fmaxf(y1, 0.0f), 1.0f);
    x1 = fminf(fmaxf(x1, 0.0f), 1.0f);
    y2 = fminf(fmaxf(y2, 0.0f), 1.0f);
    x2 = fminf(fmaxf(x2, 0.0f), 1.0f);
    float4 out;
    out.x = y1; out.y = x1; out.z = y2; out.w = x2;
    boxes[(size_t)b * KSEL + rank] = out;
}

// ---------- fallback: single-block bitonic sort+gather (ws too small) ----------
__global__ void k_sortgather(const u64* __restrict__ cand, const u32* __restrict__ candCount,
                             const float4* __restrict__ anchors, const float4* __restrict__ deltas,
                             float4* __restrict__ boxes) {
    __shared__ u64 s[CAP];
    int b = blockIdx.x;
    int tid = threadIdx.x;
    u32 cnt = candCount[b * 32];
    if (cnt > CAP) cnt = CAP;
    for (int j = tid; j < CAP; j += 1024)
        s[j] = (j < (int)cnt) ? cand[(size_t)b * CAP + j] : 0ull;
    __syncthreads();
    for (int k = 2; k <= CAP; k <<= 1) {
        for (int j = k >> 1; j > 0; j >>= 1) {
            for (int idx = tid; idx < CAP; idx += 1024) {
                int l = idx ^ j;
                if (l > idx) {
                    u64 a = s[idx], c = s[l];
                    bool dir = ((idx & k) == 0);
                    if ((a < c) == dir) { s[idx] = c; s[l] = a; }
                }
            }
            __syncthreads();
        }
    }
    for (int t = tid; t < KSEL; t += 1024) {
        u64 sk = s[t];
        u32 idx = ~(u32)(sk & 0xFFFFFFFFull);
        float4 a = anchors[(size_t)b * NN + idx];
        float4 d = deltas[(size_t)b * NN + idx];
        float dy = __fmul_rn(d.x, 0.1f);
        float dx = __fmul_rn(d.y, 0.1f);
        float dh = __fmul_rn(d.z, 0.2f);
        float dw = __fmul_rn(d.w, 0.2f);
        float h  = __fsub_rn(a.z, a.x);
        float w  = __fsub_rn(a.w, a.y);
        float cy = __fadd_rn(__fadd_rn(a.x, __fmul_rn(0.5f, h)), __fmul_rn(dy, h));
        float cx = __fadd_rn(__fadd_rn(a.y, __fmul_rn(0.5f, w)), __fmul_rn(dx, w));
        float h2 = __fmul_rn(h, expf(dh));
        float w2 = __fmul_rn(w, expf(dw));
        float y1 = __fsub_rn(cy, __fmul_rn(0.5f, h2));
        float x1 = __fsub_rn(cx, __fmul_rn(0.5f, w2));
        float y2 = __fadd_rn(y1, h2);
        float x2 = __fadd_rn(x1, w2);
        y1 = fminf(fmaxf(y1, 0.0f), 1.0f);
        x1 = fminf(fmaxf(x1, 0.0f), 1.0f);
        y2 = fminf(fmaxf(y2, 0.0f), 1.0f);
        x2 = fminf(fmaxf(x2, 0.0f), 1.0f);
        float4 out;
        out.x = y1; out.y = x1; out.z = y2; out.w = x2;
        boxes[(size_t)b * KSEL + t] = out;
    }
}

// ---------- phase 1: upper-triangle bitmask, row-major, stride NWP ----------
__global__ __launch_bounds__(256) void k_iou(const float4* __restrict__ boxes,
                                             u64* __restrict__ mask) {
    __shared__ float4 colBox[4][64];
    __shared__ float  colArea[4][64];
    int b = blockIdx.z;
    int rblk = blockIdx.x;
    int r0 = rblk * 64;
    int tid = threadIdx.x;
    int wave = tid >> 6, lane = tid & 63;
    const float4* B4 = boxes + (size_t)b * KSEL;

    int r = r0 + lane;
    float4 rb;
    if (r < KSEL) rb = B4[r];
    else { rb.x = 2.0f; rb.y = 2.0f; rb.z = 3.0f; rb.w = 3.0f; }
    float ra = __fmul_rn(__fsub_rn(rb.z, rb.x), __fsub_rn(rb.w, rb.y));

    const double M0 = 0.5 * ((double)__uint_as_float(0x3F333333u)
                           + (double)__uint_as_float(0x3F333334u));
    u64* Mb = mask + (size_t)b * NR * NWP;

    for (int jw = rblk + blockIdx.y * 4 + wave; jw < NW; jw += 4 * COLSPLIT) {
        int j = jw * 64 + lane;
        float4 cbx;
        if (j < KSEL) cbx = B4[j];
        else { cbx.x = 2.0f; cbx.y = 2.0f; cbx.z = 3.0f; cbx.w = 3.0f; }
        colBox[wave][lane] = cbx;
        colArea[wave][lane] = __fmul_rn(__fsub_rn(cbx.z, cbx.x), __fsub_rn(cbx.w, cbx.y));
        asm volatile("" ::: "memory");

        u64 word = 0ull;
        #pragma unroll
        for (int c = 0; c < 64; ++c) {
            float4 cb = colBox[wave][c];
            float ca = colArea[wave][c];
            float ih = fmaxf(__fsub_rn(fminf(rb.z, cb.z), fmaxf(rb.x, cb.x)), 0.0f);
            float iw = fmaxf(__fsub_rn(fminf(rb.w, cb.w), fmaxf(rb.y, cb.y)), 0.0f);
            float inter = __fmul_rn(ih, iw);
            float denom = __fadd_rn(__fsub_rn(__fadd_rn(ra, ca), inter), 1e-8f);
            bool pred = ((double)inter >= M0 * (double)denom);
            word |= ((u64)pred) << c;
        }
        Mb[(size_t)(r0 + lane) * NWP + jw] = word;
        asm volatile("" ::: "memory");
    }
}

// ---------- phase 2: 16-wave reduce (structural floor ~70us, 5 variants) ----------
__device__ __forceinline__ u64 readlane64(u64 v, int lane) {
    u32 lo = (u32)__builtin_amdgcn_readlane((int)(u32)v, lane);
    u32 hi = (u32)__builtin_amdgcn_readlane((int)(u32)(v >> 32), lane);
    return ((u64)hi << 32) | (u64)lo;
}
__device__ __forceinline__ u64 rfl64(u64 v) {
    u32 lo = (u32)__builtin_amdgcn_readfirstlane((int)(u32)v);
    u32 hi = (u32)__builtin_amdgcn_readfirstlane((int)(u32)(v >> 32));
    return ((u64)hi << 32) | (u64)lo;
}
__device__ __forceinline__ void barrier_lds_only() {
    asm volatile("s_waitcnt lgkmcnt(0)" ::: "memory");
    __builtin_amdgcn_s_barrier();
    asm volatile("" ::: "memory");
}

__global__ __launch_bounds__(1024) void k_reduce(const u64* __restrict__ mask,
                                                 const float4* __restrict__ boxes,
                                                 float* __restrict__ outp) {
    __shared__ u64 pub[16];
    __shared__ u64 kbLDS;
    __shared__ u32 kLDS;
    __shared__ u32 keptIdx[PC];
    int b = blockIdx.x;
    int tid = threadIdx.x;
    int wv = tid >> 6, lane = tid & 63;
    const u64* M = mask + (size_t)b * NR * NWP;
    const float4* B4 = boxes + (size_t)b * KSEL;
    int lp = lane < 46 ? lane : 46;
    u64 rwA = 0ull, rwB = 0ull;
    int k = 0, kprev = 0;
    bool done = false;

    if (tid < 16) pub[tid] = 0ull;

    ulonglong2 bufA[4], bufB[4], bufC[4];
    u64 dgA, dgB, dgC;

#define LOADG(BUF, DG, gg) do {                                               \
    int gl_ = (gg); if (gl_ > NW - 1) gl_ = NW - 1;                           \
    _Pragma("unroll")                                                         \
    for (int r_ = 0; r_ < 4; ++r_)                                            \
        BUF[r_] = *(const ulonglong2*)(M + (size_t)(gl_ * 64 + wv * 4 + r_) * NWP + 2 * lp); \
    DG = M[(size_t)(gl_ * 64 + lane) * NWP + gl_];                            \
} while (0)

#define BODY(gg, CUR, DGC, NXT, DGN) do {                                     \
    const int gb_ = (gg);                                                     \
    LOADG(NXT, DGN, gb_ + 2);                                                 \
    if (wv == 0) {                                                            \
        u64 rem = pub[0] | pub[1] | pub[2] | pub[3]                           \
                | pub[4] | pub[5] | pub[6] | pub[7]                           \
                | pub[8] | pub[9] | pub[10] | pub[11]                         \
                | pub[12] | pub[13] | pub[14] | pub[15];                      \
        rem = rfl64(rem);                                                     \
        int remaining = KSEL - gb_ * 64;                                      \
        u64 valid = (remaining >= 64) ? ~0ull : ((1ull << remaining) - 1ull); \
        u64 todo = ~rem & valid;                                              \
        u64 kb0 = 0ull;                                                       \
        int k0 = k;                                                           \
        while (todo && k0 < PC) {                                             \
            u64 t_ = todo;                                                    \
            int i0 = (int)__builtin_ctzll(t_); t_ &= t_ - 1;                  \
            bool v1 = t_ != 0ull;                                             \
            int i1 = v1 ? (int)__builtin_ctzll(t_) : i0; t_ &= t_ - 1;        \
            bool v2 = t_ != 0ull;                                             \
            int i2 = v2 ? (int)__builtin_ctzll(t_) : i0; t_ &= t_ - 1;        \
            bool v3 = t_ != 0ull;                                             \
            int i3 = v3 ? (int)__builtin_ctzll(t_) : i0;                      \
            u64 m0 = __ballot(((DGC >> i0) & 1ull) != 0ull);                  \
            u64 m1 = __ballot(((DGC >> i1) & 1ull) != 0ull);                  \
            u64 m2 = __ballot(((DGC >> i2) & 1ull) != 0ull);                  \
            u64 m3 = __ballot(((DGC >> i3) & 1ull) != 0ull);                  \
            u64 kept_ = 1ull << i0; ++k0;                                     \
            u64 sup_ = m0;                                                    \
            if (v1 && k0 < PC && !((sup_ >> i1) & 1ull)) {                    \
                kept_ |= 1ull << i1; ++k0; sup_ |= m1;                        \
            }                                                                 \
            if (v2 && k0 < PC && !((sup_ >> i2) & 1ull)) {                    \
                kept_ |= 1ull << i2; ++k0; sup_ |= m2;                        \
            }                                                                 \
            if (v3 && k0 < PC && !((sup_ >> i3) & 1ull)) {                    \
                kept_ |= 1ull << i3; ++k0; sup_ |= m3;                        \
            }                                                                 \
            kb0 |= kept_;                                                     \
            todo &= ~(sup_ | kept_);                                          \
            if (k0 >= PC) break;                                              \
        }                                                                     \
        if ((kb0 >> lane) & 1ull) {                                           \
            int rank = kprev + (int)__popcll(kb0 & ((1ull << lane) - 1ull));  \
            keptIdx[rank] = (u32)(gb_ * 64 + lane);                           \
        }                                                                     \
        kprev = k0;                                                           \
        if (lane == 0) { kbLDS = kb0; kLDS = (u32)k0; }                       \
    }                                                                         \
    barrier_lds_only();                                                       \
    u64 kb_ = kbLDS;                                                          \
    k = (int)kLDS;                                                            \
    _Pragma("unroll")                                                         \
    for (int r_ = 0; r_ < 4; ++r_)                                            \
        if ((kb_ >> (wv * 4 + r_)) & 1ull) { rwA |= CUR[r_].x; rwB |= CUR[r_].y; } \
    if (k >= PC || gb_ == NW - 1) { done = true; }                            \
    else {                                                                    \
        int nw_ = gb_ + 1;                                                    \
        u64 wpub = (nw_ & 1) ? readlane64(rwB, nw_ >> 1)                      \
                             : readlane64(rwA, nw_ >> 1);                     \
        if (lane == 0) pub[wv] = wpub;                                        \
        barrier_lds_only();                                                   \
    }                                                                         \
} while (0)

    LOADG(bufA, dgA, 0);
    LOADG(bufB, dgB, 1);
    __syncthreads();   // pub init visible

    for (int g = 0; g < NW && !done; g += 3) {
        BODY(g, bufA, dgA, bufC, dgC);
        if (done || g + 1 >= NW) break;
        BODY(g + 1, bufB, dgB, bufA, dgA);
        if (done || g + 2 >= NW) break;
        BODY(g + 2, bufC, dgC, bufB, dgB);
    }
    __syncthreads();   // keptIdx visible to all threads

    float4* O = (float4*)outp + (size_t)b * PC;
    for (int t = tid; t < PC; t += 1024) {
        float4 v; v.x = 0.0f; v.y = 0.0f; v.z = 0.0f; v.w = 0.0f;
        if (t < k) v = B4[keptIdx[t]];
        O[t] = v;
    }
#undef LOADG
#undef BODY
}

// ---------- fallback serial NMS (used only if ws too small for mask) ----------
__global__ void k_nms(const float4* __restrict__ boxes, float* __restrict__ outp) {
    __shared__ float4 chunk[512];
    __shared__ float4 keptBox[PC];
    __shared__ float  keptArea[PC];
    __shared__ u32    flag[2];
    int b = blockIdx.x;
    int tid = threadIdx.x;
    const float4* B4 = boxes + (size_t)b * KSEL;

    if (tid < 2) flag[tid] = 0u;
    for (int j = tid; j < 512; j += 256) chunk[j] = B4[j];
    __syncthreads();

    int kc = 0;
    for (int i = 0; i < KSEL && kc < PC; ++i) {
        int ci = i & 511;
        if (ci == 0 && i != 0) {
            for (int j = tid; j < 512 && (i + j) < KSEL; j += 256) chunk[j] = B4[i + j];
            __syncthreads();
        }
        float4 cb = chunk[ci];
        float careaV = __fmul_rn(__fsub_rn(cb.z, cb.x), __fsub_rn(cb.w, cb.y));
        bool sup = false;
        for (int t = tid; t < kc; t += 256) {
            float4 kb2 = keptBox[t];
            float ih = fmaxf(__fsub_rn(fminf(cb.z, kb2.z), fmaxf(cb.x, kb2.x)), 0.0f);
            float iw = fmaxf(__fsub_rn(fminf(cb.w, kb2.w), fmaxf(cb.y, kb2.y)), 0.0f);
            float inter = __fmul_rn(ih, iw);
            float denom = __fadd_rn(__fsub_rn(__fadd_rn(careaV, keptArea[t]), inter), 1e-8f);
            if (__fdiv_rn(inter, denom) > NMS_THR) sup = true;
        }
        int p = i & 1;
        if (sup) flag[p] = 1u;
        if (tid == 0) flag[p ^ 1] = 0u;
        __syncthreads();
        if (flag[p] == 0u) {
            if (tid == 0) { keptBox[kc] = cb; keptArea[kc] = careaV; }
            kc++;
        }
        __syncthreads();
    }

    float4* out4 = (float4*)outp + (size_t)b * PC;
    for (int r = tid; r < PC; r += 256) {
        float4 v;
        if (r < kc) v = keptBox[r];
        else { v.x = 0.0f; v.y = 0.0f; v.z = 0.0f; v.w = 0.0f; }
        out4[r] = v;
    }
}

extern "C" void kernel_launch(void* const* d_in, const int* in_sizes, int n_in,
                              void* d_out, int out_size, void* d_ws, size_t ws_size,
                              hipStream_t stream) {
    const float* probs   = (const float*)d_in[0];
    const float* deltas  = (const float*)d_in[1];
    const float* anchors = (const float*)d_in[2];
    float* outp = (float*)d_out;

    u32* ws32 = (u32*)d_ws;
    u32* hist1 = ws32 + HIST1_OFF;
    u32* hist2 = ws32 + HIST2_OFF;
    u32* sel   = ws32 + SEL_OFF;
    u32* candCount = ws32 + CNT_OFF;
    u32* rankArr   = ws32 + RANK_OFF;
    u64* cand   = (u64*)(ws32 + ZERO_WORDS);
    float* boxesF = (float*)(cand + (size_t)BB * CAP);
    float4* boxes = (float4*)boxesF;
    u64* mask = (u64*)(boxesF + (size_t)BB * KSEL * 4);

    size_t needed = (size_t)ZERO_WORDS * 4 + (size_t)BB * CAP * 8
                  + (size_t)BB * KSEL * 16 + (size_t)BB * NR * NWP * 8;

    hipLaunchKernelGGL(k_zero, dim3((ZERO_WORDS + 255) / 256), dim3(256), 0, stream, ws32);
    hipLaunchKernelGGL(k_hist1, dim3(HB, BB), dim3(256), 0, stream, (const float2*)probs, hist1);
    hipLaunchKernelGGL(k_sel1, dim3(BB), dim3(256), 0, stream, hist1, sel);
    hipLaunchKernelGGL(k_hist2, dim3(HB, BB), dim3(256), 0, stream, (const float2*)probs, sel, hist2);
    hipLaunchKernelGGL(k_sel2, dim3(BB), dim3(256), 0, stream, hist2, sel);
    hipLaunchKernelGGL(k_compact, dim3(CB, BB), dim3(256), 0, stream, (const float2*)probs, sel, candCount, cand);
    if (ws_size >= needed) {
        hipLaunchKernelGGL(k_rank, dim3(CAP / 512, CS, BB), dim3(512), 0, stream, cand, candCount, rankArr);
        hipLaunchKernelGGL(k_scatterdecode, dim3(CAP / 256, BB), dim3(256), 0, stream,
                           cand, candCount, rankArr,
                           (const float4*)anchors, (const float4*)deltas, boxes);
        hipLaunchKernelGGL(k_iou, dim3(NW, COLSPLIT, BB), dim3(256), 0, stream, boxes, mask);
        hipLaunchKernelGGL(k_reduce, dim3(BB), dim3(1024), 0, stream, mask, boxes, outp);
    } else {
        hipLaunchKernelGGL(k_sortgather, dim3(BB), dim3(1024), 0, stream,
                           cand, candCount, (const float4*)anchors, (const float4*)deltas, boxes);
        hipLaunchKernelGGL(k_nms, dim3(BB), dim3(256), 0, stream, boxes, outp);
    }
}